// Round 10
// baseline (585.360 us; speedup 1.0000x reference)
//
#include <hip/hip_runtime.h>
#include <math.h>

#define N_PTS 8192
#define ICP_STEPS 21      // STEPLIM + 1 scan iterations
#define ICP_TOL 1e-4

#define NBLK 256          // one block per CU; block owns 32 queries
#define BSIZE 1024        // 16 waves = 4 waves/SIMD (TLP for latency hiding)
#define QPW 8             // queries per wave-subgroup (8-way ILP, proven)
#define ACC_STRIDE 8      // one f64 per 64B line: RMWs spread across channels

struct IcpCtl {
  double err;
  double Rc[9];     // cumulative rotation (row-major): pc = Rc*p1 + tc
  double tc[3];
  int done;
  unsigned ticket;  // reduce-completion ticket (selects solver block)
};

// ---------------------------------------------------------------------------
// prep: p2aug = (x,y,z,|b|^2) float4; ctl/acc reset (runs every replay)
// ---------------------------------------------------------------------------
__global__ __launch_bounds__(256) void icp_prep(const float* __restrict__ p2,
                                                float4* __restrict__ p2aug,
                                                IcpCtl* __restrict__ ctl,
                                                double* __restrict__ acc) {
  int t = blockIdx.x * 256 + threadIdx.x;   // grid covers exactly N_PTS
  float x = p2[3*t], y = p2[3*t+1], z = p2[3*t+2];
  p2aug[t] = make_float4(x, y, z, fmaf(x, x, fmaf(y, y, z*z)));
  if (t < 16 * ACC_STRIDE) acc[t] = 0.0;
  if (t == 0) {
    ctl->err = 0.0; ctl->done = 0; ctl->ticket = 0u;
    #pragma unroll
    for (int i = 0; i < 9; ++i) ctl->Rc[i] = (i % 4 == 0) ? 1.0 : 0.0;
    ctl->tc[0] = ctl->tc[1] = ctl->tc[2] = 0.0;
  }
}

// ---------------------------------------------------------------------------
// Register-only 3x3 Kabsch from raw sums (no runtime-indexed arrays).
// s[0]=sum dmin, s[1..3]=sum src, s[4..6]=sum dst, s[7..15]=sum src_i*dst_j.
// R = V diag(1,1,detV) U~^T (right-handed U~) == reference's sign-fixed SVD.
// ---------------------------------------------------------------------------
__device__ __forceinline__ void kabsch_solve(const double* s, double* R, double* T) {
  const double n = (double)N_PTS;
  const double c1x = s[1]/n, c1y = s[2]/n, c1z = s[3]/n;
  const double c2x = s[4]/n, c2y = s[5]/n, c2z = s[6]/n;
  const double h00 = s[7]  - n*c1x*c2x, h01 = s[8]  - n*c1x*c2y, h02 = s[9]  - n*c1x*c2z;
  const double h10 = s[10] - n*c1y*c2x, h11 = s[11] - n*c1y*c2y, h12 = s[12] - n*c1y*c2z;
  const double h20 = s[13] - n*c1z*c2x, h21 = s[14] - n*c1z*c2y, h22 = s[15] - n*c1z*c2z;

  double a00 = h00*h00 + h10*h10 + h20*h20;
  double a01 = h00*h01 + h10*h11 + h20*h21;
  double a02 = h00*h02 + h10*h12 + h20*h22;
  double a11 = h01*h01 + h11*h11 + h21*h21;
  double a12 = h01*h02 + h11*h12 + h21*h22;
  double a22 = h02*h02 + h12*h12 + h22*h22;

  double v00=1.0, v01=0.0, v02=0.0;
  double v10=0.0, v11=1.0, v12=0.0;
  double v20=0.0, v21=0.0, v22=1.0;

#define ROT3(app, aqq, apq, arp, arq, vpa, vqa, vpb, vqb, vpc, vqc)              \
  {                                                                              \
    double apq_ = apq;                                                           \
    if (fabs(apq_) > 1e-300) {                                                   \
      double tau = (aqq - app) / (2.0 * apq_);                                   \
      double tt  = (tau >= 0.0 ? 1.0 : -1.0) / (fabs(tau) + sqrt(1.0 + tau*tau));\
      double c_  = 1.0 / sqrt(1.0 + tt*tt), sn = tt * c_;                        \
      app -= tt * apq_;  aqq += tt * apq_;  apq = 0.0;                           \
      double t1 = arp, t2 = arq;                                                 \
      arp = c_*t1 - sn*t2;  arq = sn*t1 + c_*t2;                                 \
      t1 = vpa; t2 = vqa; vpa = c_*t1 - sn*t2; vqa = sn*t1 + c_*t2;              \
      t1 = vpb; t2 = vqb; vpb = c_*t1 - sn*t2; vqb = sn*t1 + c_*t2;              \
      t1 = vpc; t2 = vqc; vpc = c_*t1 - sn*t2; vqc = sn*t1 + c_*t2;              \
    }                                                                            \
  }

  #pragma unroll
  for (int sweep = 0; sweep < 6; ++sweep) {
    ROT3(a00, a11, a01, a02, a12, v00, v01, v10, v11, v20, v21);  // (0,1)
    ROT3(a00, a22, a02, a01, a12, v00, v02, v10, v12, v20, v22);  // (0,2)
    ROT3(a11, a22, a12, a01, a02, v01, v02, v11, v12, v21, v22);  // (1,2)
  }
#undef ROT3

  double l0 = a00, l1 = a11, l2 = a22;
  double e0x=v00, e0y=v10, e0z=v20;
  double e1x=v01, e1y=v11, e1z=v21;
  double e2x=v02, e2y=v12, e2z=v22;
#define CSWAP(la, lb, xa, ya, za, xb, yb, zb)                                    \
  if (lb > la) { double t_;                                                      \
    t_ = la; la = lb; lb = t_;  t_ = xa; xa = xb; xb = t_;                       \
    t_ = ya; ya = yb; yb = t_;  t_ = za; za = zb; zb = t_; }
  CSWAP(l0, l1, e0x, e0y, e0z, e1x, e1y, e1z);
  CSWAP(l0, l2, e0x, e0y, e0z, e2x, e2y, e2z);
  CSWAP(l1, l2, e1x, e1y, e1z, e2x, e2y, e2z);
#undef CSWAP

  double detV = e0x*(e1y*e2z - e1z*e2y) - e0y*(e1x*e2z - e1z*e2x)
              + e0z*(e1x*e2y - e1y*e2x);
  const double dsg = (detV >= 0.0) ? 1.0 : -1.0;

  double u0x = h00*e0x + h01*e0y + h02*e0z;
  double u0y = h10*e0x + h11*e0y + h12*e0z;
  double u0z = h20*e0x + h21*e0y + h22*e0z;
  double n0 = sqrt(u0x*u0x + u0y*u0y + u0z*u0z);
  if (!(n0 > 1e-150)) {
    R[0]=1.0; R[1]=0.0; R[2]=0.0; R[3]=0.0; R[4]=1.0; R[5]=0.0;
    R[6]=0.0; R[7]=0.0; R[8]=1.0;
    T[0]=c2x-c1x; T[1]=c2y-c1y; T[2]=c2z-c1z;
    return;
  }
  u0x /= n0; u0y /= n0; u0z /= n0;
  double u1x = h00*e1x + h01*e1y + h02*e1z;
  double u1y = h10*e1x + h11*e1y + h12*e1z;
  double u1z = h20*e1x + h21*e1y + h22*e1z;
  const double d10 = u1x*u0x + u1y*u0y + u1z*u0z;
  u1x -= d10*u0x; u1y -= d10*u0y; u1z -= d10*u0z;
  double n1 = sqrt(u1x*u1x + u1y*u1y + u1z*u1z);
  if (!(n1 > 1e-150)) {
    R[0]=1.0; R[1]=0.0; R[2]=0.0; R[3]=0.0; R[4]=1.0; R[5]=0.0;
    R[6]=0.0; R[7]=0.0; R[8]=1.0;
    T[0]=c2x-c1x; T[1]=c2y-c1y; T[2]=c2z-c1z;
    return;
  }
  u1x /= n1; u1y /= n1; u1z /= n1;
  const double u2x = u0y*u1z - u0z*u1y;
  const double u2y = u0z*u1x - u0x*u1z;
  const double u2z = u0x*u1y - u0y*u1x;

  R[0] = e0x*u0x + e1x*u1x + dsg*e2x*u2x;
  R[1] = e0x*u0y + e1x*u1y + dsg*e2x*u2y;
  R[2] = e0x*u0z + e1x*u1z + dsg*e2x*u2z;
  R[3] = e0y*u0x + e1y*u1x + dsg*e2y*u2x;
  R[4] = e0y*u0y + e1y*u1y + dsg*e2y*u2y;
  R[5] = e0y*u0z + e1y*u1z + dsg*e2y*u2z;
  R[6] = e0z*u0x + e1z*u1x + dsg*e2z*u2x;
  R[7] = e0z*u0y + e1z*u1y + dsg*e2z*u2y;
  R[8] = e0z*u0z + e1z*u1z + dsg*e2z*u2z;
  T[0] = c2x - (R[0]*c1x + R[1]*c1y + R[2]*c1z);
  T[1] = c2y - (R[3]*c1x + R[4]*c1y + R[5]*c1z);
  T[2] = c2z - (R[6]*c1x + R[7]*c1y + R[8]*c1z);
}

// ---------------------------------------------------------------------------
// One FUSED ICP iteration per dispatch (22 dispatches total).
// Compute structure = R9 (16 waves, full-LDS candidates, static indexing,
// zero scratch). Reduce+solve fused via R7's proven sync: relaxed memory-side
// f64 atomicAdd (line-padded) + same-wave vmcnt(0) + relaxed ticket ->
// last block solves Kabsch, composes, writes out, resets acc/ticket.
// ---------------------------------------------------------------------------
__global__ __launch_bounds__(BSIZE, 4) void icp_iter(const float* __restrict__ p1,
                                                     const float4* __restrict__ p2aug,
                                                     IcpCtl* __restrict__ ctl,
                                                     double* __restrict__ acc,
                                                     float* __restrict__ out) {
  if (ctl->done) return;                    // uniform across grid
  __shared__ float4 cand[N_PTS];            // 128 KiB
  __shared__ unsigned long long pkbuf[32][4];
  __shared__ float4 qlds[32];
  __shared__ double pairbuf[32][17];        // +1 pad
  __shared__ double tot[16];
  __shared__ int lastFlag;

  const int tid  = threadIdx.x;
  const int lane = tid & 63;
  const int w    = tid >> 6;
  const int g    = w >> 2;                  // query subgroup 0..3
  const int s    = w & 3;                   // candidate slice 0..3

  // ---- stage ALL candidates into LDS (each thread 8 float4, coalesced) ----
  #pragma unroll
  for (int k = 0; k < 8; ++k) {
    const int i = (k << 10) + tid;
    cand[i] = p2aug[i];
  }

  // ---- query transforms (wave-uniform; done while staging is in flight) ----
  const double R0 = ctl->Rc[0], R1 = ctl->Rc[1], R2 = ctl->Rc[2];
  const double R3 = ctl->Rc[3], R4 = ctl->Rc[4], R5 = ctl->Rc[5];
  const double R6 = ctl->Rc[6], R7 = ctl->Rc[7], R8 = ctl->Rc[8];
  const double T0 = ctl->tc[0], T1 = ctl->tc[1], T2 = ctl->tc[2];

  const int qbase = (blockIdx.x << 5) + (g << 3);
  float axv[QPW], ayv[QPW], azv[QPW], best[QPW];
  int bidx[QPW];
  float qxr[QPW], qyr[QPW], qzr[QPW];       // static-indexed only
  #pragma unroll
  for (int j = 0; j < QPW; ++j) {
    const int q = qbase + j;
    const double X = (double)p1[3*q], Y = (double)p1[3*q+1], Z = (double)p1[3*q+2];
    qxr[j] = (float)(R0*X + R1*Y + R2*Z + T0);  // fp32-rounded, matches ref pc
    qyr[j] = (float)(R3*X + R4*Y + R5*Z + T1);
    qzr[j] = (float)(R6*X + R7*Y + R8*Z + T2);
    axv[j] = -2.f*qxr[j]; ayv[j] = -2.f*qyr[j]; azv[j] = -2.f*qzr[j];
    best[j] = __builtin_inff(); bidx[j] = 0;
  }
  // publish query coords for the pair-sum phase (static unroll, lane 0, s==0)
  if (s == 0 && lane == 0) {
    #pragma unroll
    for (int j = 0; j < QPW; ++j)
      qlds[(g << 3) + j] = make_float4(qxr[j], qyr[j], qzr[j], 0.f);
  }
  __syncthreads();

  // ---- NN scan: slice s = cands [s*2048, s*2048+2048), lane-contiguous ----
  const int cb = s << 11;
  #pragma unroll 8
  for (int k = 0; k < 32; ++k) {
    const int cidx = cb + (k << 6) + lane;
    float4 c = cand[cidx];                  // ds_read_b128, conflict-free
    #pragma unroll
    for (int j = 0; j < QPW; ++j) {
      float d = fmaf(axv[j], c.x, fmaf(ayv[j], c.y, fmaf(azv[j], c.z, c.w)));
      if (d < best[j]) { best[j] = d; bidx[j] = cidx; }
    }
  }

  // ---- cross-lane argmin: packed (ordered-dist, idx) u64 butterfly ----
  // jnp.argmin tie semantics: lowest distance, then lowest index.
  unsigned long long pk[QPW];
  #pragma unroll
  for (int j = 0; j < QPW; ++j) {
    unsigned u = __float_as_uint(best[j]);
    u ^= (unsigned)((int)u >> 31) | 0x80000000u;   // monotone float->uint
    pk[j] = ((unsigned long long)u << 32) | (unsigned)bidx[j];
  }
  #pragma unroll
  for (int j = 0; j < QPW; ++j) {
    #pragma unroll
    for (int o = 1; o < 64; o <<= 1) {
      unsigned long long other = __shfl_xor(pk[j], o, 64);
      pk[j] = (other < pk[j]) ? other : pk[j];
    }
  }
  if (lane == 0) {                          // static unroll -> registers
    #pragma unroll
    for (int j = 0; j < QPW; ++j)
      pkbuf[(g << 3) + j][s] = pk[j];
  }
  __syncthreads();

  // ---- combine 4 slices + pair sums: tid<32, one query each, all static ----
  if (tid < 32) {
    unsigned long long m = pkbuf[tid][0];
    unsigned long long m1 = pkbuf[tid][1]; m = (m1 < m) ? m1 : m;
    unsigned long long m2 = pkbuf[tid][2]; m = (m2 < m) ? m2 : m;
    unsigned long long m3 = pkbuf[tid][3]; m = (m3 < m) ? m3 : m;
    const unsigned idx = (unsigned)(m & 0xffffffffull);
    const float4 q4 = qlds[tid];
    const float4 b4 = cand[idx];            // LDS gather (32 lanes, cheap)
    const double ax = q4.x, ay = q4.y, az = q4.z;
    const double bx = b4.x, by = b4.y, bz = b4.z;
    const double d2 = (ax*ax + ay*ay + az*az) + (bx*bx + by*by + bz*bz)
                    - 2.0*(ax*bx + ay*by + az*bz);
    pairbuf[tid][0]  = sqrt(fmax(d2, 1e-12));
    pairbuf[tid][1]  = ax;    pairbuf[tid][2]  = ay;    pairbuf[tid][3]  = az;
    pairbuf[tid][4]  = bx;    pairbuf[tid][5]  = by;    pairbuf[tid][6]  = bz;
    pairbuf[tid][7]  = ax*bx; pairbuf[tid][8]  = ax*by; pairbuf[tid][9]  = ax*bz;
    pairbuf[tid][10] = ay*bx; pairbuf[tid][11] = ay*by; pairbuf[tid][12] = ay*bz;
    pairbuf[tid][13] = az*bx; pairbuf[tid][14] = az*by; pairbuf[tid][15] = az*bz;
  }
  __syncthreads();

  // ---- 16 column sums -> relaxed memory-side atomicAdd (line-padded) ----
  if (tid < 16) {
    double ssum = 0.0;
    #pragma unroll
    for (int i = 0; i < 32; ++i) ssum += pairbuf[i][tid];
    atomicAdd(acc + tid * ACC_STRIDE, ssum);   // device-scope, relaxed
  }
  if (tid == 0) {
    // Lanes 0-15 of THIS wave issued the adds; vmcnt is per-wave, so this
    // waits for their completion at the coherence point. A WAIT, not a flush.
    asm volatile("s_waitcnt vmcnt(0)" ::: "memory");
    unsigned old = __hip_atomic_fetch_add(&ctl->ticket, 1u,
                      __ATOMIC_RELAXED, __HIP_MEMORY_SCOPE_AGENT);
    lastFlag = (old == NBLK - 1u) ? 1 : 0;
  }
  __syncthreads();
  if (!lastFlag) return;

  // ---- last block: totals via relaxed RMW read (memory-side, R7-proven) ----
  if (tid < 16) tot[tid] = atomicAdd(acc + tid * ACC_STRIDE, 0.0);
  __syncthreads();
  if (tid == 0) {
    double sm[16];
    #pragma unroll
    for (int i = 0; i < 16; ++i) sm[i] = tot[i];
    double R[9], T[3];
    kabsch_solve(sm, R, T);
    // compose: pc_new = R*(Rc*p1 + tc) + T = (R*Rc)*p1 + (R*tc + T)
    double Rc[9] = {R0,R1,R2,R3,R4,R5,R6,R7,R8};
    double tc[3] = {T0,T1,T2};
    double Rn[9], tn[3];
    #pragma unroll
    for (int i = 0; i < 3; ++i) {
      #pragma unroll
      for (int j = 0; j < 3; ++j)
        Rn[3*i+j] = R[3*i+0]*Rc[0+j] + R[3*i+1]*Rc[3+j] + R[3*i+2]*Rc[6+j];
      tn[i] = R[3*i+0]*tc[0] + R[3*i+1]*tc[1] + R[3*i+2]*tc[2] + T[i];
    }
    #pragma unroll
    for (int i = 0; i < 9; ++i) ctl->Rc[i] = Rn[i];
    #pragma unroll
    for (int i = 0; i < 3; ++i) ctl->tc[i] = tn[i];
    const double errnew = sm[0];            // B == 1
    ctl->done = (fabs(ctl->err - errnew) < ICP_TOL) ? 1 : 0;
    ctl->err  = errnew;
    // out = [Rc | tc] 3x4 (kabsch(p1, Rc*p1+tc) == (Rc,tc) exactly).
    #pragma unroll
    for (int i = 0; i < 3; ++i) {
      out[4*i + 0] = (float)Rn[3*i + 0];
      out[4*i + 1] = (float)Rn[3*i + 1];
      out[4*i + 2] = (float)Rn[3*i + 2];
      out[4*i + 3] = (float)tn[i];
    }
    // reset for next dispatch (plain stores; end-of-kernel release flushes)
    #pragma unroll
    for (int i = 0; i < 16; ++i) acc[i * ACC_STRIDE] = 0.0;
    ctl->ticket = 0u;
  }
}

// ---------------------------------------------------------------------------
extern "C" void kernel_launch(void* const* d_in, const int* in_sizes, int n_in,
                              void* d_out, int out_size, void* d_ws, size_t ws_size,
                              hipStream_t stream) {
  const float* p1 = (const float*)d_in[0];
  const float* p2 = (const float*)d_in[1];
  float* out = (float*)d_out;

  char* ws = (char*)d_ws;
  float4* p2aug = (float4*)ws;                       // 128 KiB
  IcpCtl* ctl   = (IcpCtl*)(ws + 128*1024);          // ~120 B
  double* acc   = (double*)(ws + 128*1024 + 512);    // 1 KiB (16 x 64B lines)

  icp_prep<<<N_PTS/256, 256, 0, stream>>>(p2, p2aug, ctl, acc);
  for (int it = 0; it < ICP_STEPS; ++it)
    icp_iter<<<NBLK, BSIZE, 0, stream>>>(p1, p2aug, ctl, acc, out);
}

// Round 11
// 546.729 us; speedup vs baseline: 1.0707x; 1.0707x over previous
//
#include <hip/hip_runtime.h>
#include <math.h>

#define N_PTS 8192
#define ICP_STEPS 21      // STEPLIM + 1 scan iterations
#define ICP_TOL 1e-4

#define NBLK 256          // one block per CU; block owns 32 queries
#define BSIZE 1024        // 16 waves = 4 waves/SIMD
#define QPW 8             // queries per wave-subgroup (8-way ILP, proven)

// state_j lives in slot j%2; part of step k lives in slot k%2.
struct IcpSt {
  double Rc[9];     // cumulative rotation (row-major): pc = Rc*p1 + tc
  double tc[3];
  double err;
  int done;
};

// ---------------------------------------------------------------------------
// prep: p2aug = (x,y,z,|b|^2) float4; st[0] = identity state
// ---------------------------------------------------------------------------
__global__ __launch_bounds__(256) void icp_prep(const float* __restrict__ p2,
                                                float4* __restrict__ p2aug,
                                                IcpSt* __restrict__ st0) {
  int t = blockIdx.x * 256 + threadIdx.x;   // grid covers exactly N_PTS
  float x = p2[3*t], y = p2[3*t+1], z = p2[3*t+2];
  p2aug[t] = make_float4(x, y, z, fmaf(x, x, fmaf(y, y, z*z)));
  if (t == 0) {
    #pragma unroll
    for (int i = 0; i < 9; ++i) st0->Rc[i] = (i % 4 == 0) ? 1.0 : 0.0;
    st0->tc[0] = st0->tc[1] = st0->tc[2] = 0.0;
    st0->err = 0.0; st0->done = 0;
  }
}

// ---------------------------------------------------------------------------
// Register-only 3x3 Kabsch from raw sums (no runtime-indexed arrays).
// s[0]=sum dmin, s[1..3]=sum src, s[4..6]=sum dst, s[7..15]=sum src_i*dst_j.
// R = V diag(1,1,detV) U~^T (right-handed U~) == reference's sign-fixed SVD.
// ---------------------------------------------------------------------------
__device__ __forceinline__ void kabsch_solve(const double* s, double* R, double* T) {
  const double n = (double)N_PTS;
  const double c1x = s[1]/n, c1y = s[2]/n, c1z = s[3]/n;
  const double c2x = s[4]/n, c2y = s[5]/n, c2z = s[6]/n;
  const double h00 = s[7]  - n*c1x*c2x, h01 = s[8]  - n*c1x*c2y, h02 = s[9]  - n*c1x*c2z;
  const double h10 = s[10] - n*c1y*c2x, h11 = s[11] - n*c1y*c2y, h12 = s[12] - n*c1y*c2z;
  const double h20 = s[13] - n*c1z*c2x, h21 = s[14] - n*c1z*c2y, h22 = s[15] - n*c1z*c2z;

  double a00 = h00*h00 + h10*h10 + h20*h20;
  double a01 = h00*h01 + h10*h11 + h20*h21;
  double a02 = h00*h02 + h10*h12 + h20*h22;
  double a11 = h01*h01 + h11*h11 + h21*h21;
  double a12 = h01*h02 + h11*h12 + h21*h22;
  double a22 = h02*h02 + h12*h12 + h22*h22;

  double v00=1.0, v01=0.0, v02=0.0;
  double v10=0.0, v11=1.0, v12=0.0;
  double v20=0.0, v21=0.0, v22=1.0;

#define ROT3(app, aqq, apq, arp, arq, vpa, vqa, vpb, vqb, vpc, vqc)              \
  {                                                                              \
    double apq_ = apq;                                                           \
    if (fabs(apq_) > 1e-300) {                                                   \
      double tau = (aqq - app) / (2.0 * apq_);                                   \
      double tt  = (tau >= 0.0 ? 1.0 : -1.0) / (fabs(tau) + sqrt(1.0 + tau*tau));\
      double c_  = 1.0 / sqrt(1.0 + tt*tt), sn = tt * c_;                        \
      app -= tt * apq_;  aqq += tt * apq_;  apq = 0.0;                           \
      double t1 = arp, t2 = arq;                                                 \
      arp = c_*t1 - sn*t2;  arq = sn*t1 + c_*t2;                                 \
      t1 = vpa; t2 = vqa; vpa = c_*t1 - sn*t2; vqa = sn*t1 + c_*t2;              \
      t1 = vpb; t2 = vqb; vpb = c_*t1 - sn*t2; vqb = sn*t1 + c_*t2;              \
      t1 = vpc; t2 = vqc; vpc = c_*t1 - sn*t2; vqc = sn*t1 + c_*t2;              \
    }                                                                            \
  }

  #pragma unroll
  for (int sweep = 0; sweep < 6; ++sweep) {
    ROT3(a00, a11, a01, a02, a12, v00, v01, v10, v11, v20, v21);  // (0,1)
    ROT3(a00, a22, a02, a01, a12, v00, v02, v10, v12, v20, v22);  // (0,2)
    ROT3(a11, a22, a12, a01, a02, v01, v02, v11, v12, v21, v22);  // (1,2)
  }
#undef ROT3

  double l0 = a00, l1 = a11, l2 = a22;
  double e0x=v00, e0y=v10, e0z=v20;
  double e1x=v01, e1y=v11, e1z=v21;
  double e2x=v02, e2y=v12, e2z=v22;
#define CSWAP(la, lb, xa, ya, za, xb, yb, zb)                                    \
  if (lb > la) { double t_;                                                      \
    t_ = la; la = lb; lb = t_;  t_ = xa; xa = xb; xb = t_;                       \
    t_ = ya; ya = yb; yb = t_;  t_ = za; za = zb; zb = t_; }
  CSWAP(l0, l1, e0x, e0y, e0z, e1x, e1y, e1z);
  CSWAP(l0, l2, e0x, e0y, e0z, e2x, e2y, e2z);
  CSWAP(l1, l2, e1x, e1y, e1z, e2x, e2y, e2z);
#undef CSWAP

  double detV = e0x*(e1y*e2z - e1z*e2y) - e0y*(e1x*e2z - e1z*e2x)
              + e0z*(e1x*e2y - e1y*e2x);
  const double dsg = (detV >= 0.0) ? 1.0 : -1.0;

  double u0x = h00*e0x + h01*e0y + h02*e0z;
  double u0y = h10*e0x + h11*e0y + h12*e0z;
  double u0z = h20*e0x + h21*e0y + h22*e0z;
  double n0 = sqrt(u0x*u0x + u0y*u0y + u0z*u0z);
  if (!(n0 > 1e-150)) {
    R[0]=1.0; R[1]=0.0; R[2]=0.0; R[3]=0.0; R[4]=1.0; R[5]=0.0;
    R[6]=0.0; R[7]=0.0; R[8]=1.0;
    T[0]=c2x-c1x; T[1]=c2y-c1y; T[2]=c2z-c1z;
    return;
  }
  u0x /= n0; u0y /= n0; u0z /= n0;
  double u1x = h00*e1x + h01*e1y + h02*e1z;
  double u1y = h10*e1x + h11*e1y + h12*e1z;
  double u1z = h20*e1x + h21*e1y + h22*e1z;
  const double d10 = u1x*u0x + u1y*u0y + u1z*u0z;
  u1x -= d10*u0x; u1y -= d10*u0y; u1z -= d10*u0z;
  double n1 = sqrt(u1x*u1x + u1y*u1y + u1z*u1z);
  if (!(n1 > 1e-150)) {
    R[0]=1.0; R[1]=0.0; R[2]=0.0; R[3]=0.0; R[4]=1.0; R[5]=0.0;
    R[6]=0.0; R[7]=0.0; R[8]=1.0;
    T[0]=c2x-c1x; T[1]=c2y-c1y; T[2]=c2z-c1z;
    return;
  }
  u1x /= n1; u1y /= n1; u1z /= n1;
  const double u2x = u0y*u1z - u0z*u1y;
  const double u2y = u0z*u1x - u0x*u1z;
  const double u2z = u0x*u1y - u0y*u1x;

  R[0] = e0x*u0x + e1x*u1x + dsg*e2x*u2x;
  R[1] = e0x*u0y + e1x*u1y + dsg*e2x*u2y;
  R[2] = e0x*u0z + e1x*u1z + dsg*e2x*u2z;
  R[3] = e0y*u0x + e1y*u1x + dsg*e2y*u2x;
  R[4] = e0y*u0y + e1y*u1y + dsg*e2y*u2y;
  R[5] = e0y*u0z + e1y*u1z + dsg*e2y*u2z;
  R[6] = e0z*u0x + e1z*u1x + dsg*e2z*u2x;
  R[7] = e0z*u0y + e1z*u1y + dsg*e2z*u2y;
  R[8] = e0z*u0z + e1z*u1z + dsg*e2z*u2z;
  T[0] = c2x - (R[0]*c1x + R[1]*c1y + R[2]*c1z);
  T[1] = c2y - (R[3]*c1x + R[4]*c1y + R[5]*c1z);
  T[2] = c2z - (R[6]*c1x + R[7]*c1y + R[8]*c1z);
}

// solve step: sums s[16] + stIn state -> composed Rn/tn, errnew, done flag
__device__ __forceinline__ void solve_compose(const double* s, const IcpSt* stIn,
                                              double* Rn, double* tn,
                                              double* errnew, int* dn) {
  double R[9], T[3];
  kabsch_solve(s, R, T);
  double Rc[9], tc[3];
  #pragma unroll
  for (int i = 0; i < 9; ++i) Rc[i] = stIn->Rc[i];
  #pragma unroll
  for (int i = 0; i < 3; ++i) tc[i] = stIn->tc[i];
  // pc_new = R*(Rc*p1 + tc) + T = (R*Rc)*p1 + (R*tc + T)
  #pragma unroll
  for (int i = 0; i < 3; ++i) {
    #pragma unroll
    for (int j = 0; j < 3; ++j)
      Rn[3*i+j] = R[3*i+0]*Rc[0+j] + R[3*i+1]*Rc[3+j] + R[3*i+2]*Rc[6+j];
    tn[i] = R[3*i+0]*tc[0] + R[3*i+1]*tc[1] + R[3*i+2]*tc[2] + T[i];
  }
  *errnew = s[0];                           // B == 1
  *dn = (fabs(stIn->err - *errnew) < ICP_TOL) ? 1 : 0;
}

// ---------------------------------------------------------------------------
// Fused dispatch k (k=0..20): [solve step k-1 from partIn + stIn -> state_k,
// done-check] then [NN for step k with state_k -> partOut]. All blocks
// compute the solve redundantly (bitwise-identical f64) -> benign identical
// stOut writes; double-buffered st/part eliminate intra-dispatch races; no
// atomics anywhere (R10 lesson: contended RMW round-trips cost ~30 us).
// ---------------------------------------------------------------------------
__global__ __launch_bounds__(BSIZE) void icp_iter(const float* __restrict__ p1,
                                                  const float4* __restrict__ p2aug,
                                                  const IcpSt* __restrict__ stIn,
                                                  IcpSt* __restrict__ stOut,
                                                  const double* __restrict__ partIn,
                                                  double* __restrict__ partOut,
                                                  const int k) {
  __shared__ float4 cand[N_PTS];            // 128 KiB
  __shared__ double redbuf[64];             // 4 waves x 16 partials (solve)
  __shared__ double RT[12];                 // broadcast Rn, tn
  __shared__ int sdone;
  __shared__ unsigned long long pkbuf[32][4];
  __shared__ float4 qlds[32];
  __shared__ double pairbuf[32][17];        // +1 pad

  const int tid  = threadIdx.x;
  const int lane = tid & 63;
  const int w    = tid >> 6;
  const int g    = w >> 2;                  // query subgroup 0..3
  const int s    = w & 3;                   // candidate slice 0..3

  // ---- frozen? propagate state and stop (uniform branch) ----
  if (stIn->done) {
    if (blockIdx.x == 0 && tid == 0) {
      #pragma unroll
      for (int i = 0; i < 9; ++i) stOut->Rc[i] = stIn->Rc[i];
      #pragma unroll
      for (int i = 0; i < 3; ++i) stOut->tc[i] = stIn->tc[i];
      stOut->err = stIn->err; stOut->done = 1;
    }
    return;
  }

  // ---- stage ALL candidates into LDS (issues loads + ds_writes) ----
  #pragma unroll
  for (int k2 = 0; k2 < 8; ++k2) {
    const int i = (k2 << 10) + tid;
    cand[i] = p2aug[i];
  }

  // ---- solve phase for step k-1 (waves 0-3 reduce; tid0 solves) ----
  double R0, R1, R2, R3, R4, R5, R6, R7, R8, T0, T1, T2;
  if (k > 0) {
    double vv[16];
    if (tid < 256) {
      const double* row = partIn + (tid << 4);
      #pragma unroll
      for (int c = 0; c < 16; ++c) vv[c] = row[c];
    } else {
      #pragma unroll
      for (int c = 0; c < 16; ++c) vv[c] = 0.0;
    }
    if (w < 4) {
      #pragma unroll
      for (int q = 0; q < 16; ++q) {
        double x = vv[q];
        for (int o = 32; o > 0; o >>= 1) x += __shfl_down(x, o, 64);
        if (lane == 0) redbuf[w*16 + q] = x;
      }
    }
    __syncthreads();
    if (tid == 0) {
      double sm[16];
      #pragma unroll
      for (int i = 0; i < 16; ++i)
        sm[i] = redbuf[i] + redbuf[16+i] + redbuf[32+i] + redbuf[48+i];
      double Rn[9], tn[3], errnew; int dn;
      solve_compose(sm, stIn, Rn, tn, &errnew, &dn);
      // stOut: 256 blocks write bitwise-identical values (benign race)
      #pragma unroll
      for (int i = 0; i < 9; ++i) stOut->Rc[i] = Rn[i];
      #pragma unroll
      for (int i = 0; i < 3; ++i) stOut->tc[i] = tn[i];
      stOut->err = errnew; stOut->done = dn;
      #pragma unroll
      for (int i = 0; i < 9; ++i) RT[i] = Rn[i];
      RT[9] = tn[0]; RT[10] = tn[1]; RT[11] = tn[2];
      sdone = dn;
    }
    __syncthreads();
    if (sdone) return;                      // step k frozen (uniform)
    R0 = RT[0]; R1 = RT[1]; R2 = RT[2];
    R3 = RT[3]; R4 = RT[4]; R5 = RT[5];
    R6 = RT[6]; R7 = RT[7]; R8 = RT[8];
    T0 = RT[9]; T1 = RT[10]; T2 = RT[11];
  } else {
    R0 = stIn->Rc[0]; R1 = stIn->Rc[1]; R2 = stIn->Rc[2];
    R3 = stIn->Rc[3]; R4 = stIn->Rc[4]; R5 = stIn->Rc[5];
    R6 = stIn->Rc[6]; R7 = stIn->Rc[7]; R8 = stIn->Rc[8];
    T0 = stIn->tc[0]; T1 = stIn->tc[1]; T2 = stIn->tc[2];
  }

  // ---- query transforms: wave subgroup g owns queries qbase..qbase+7 ----
  const int qbase = (blockIdx.x << 5) + (g << 3);
  float axv[QPW], ayv[QPW], azv[QPW], best[QPW];
  int bidx[QPW];
  float qxr[QPW], qyr[QPW], qzr[QPW];       // static-indexed only
  #pragma unroll
  for (int j = 0; j < QPW; ++j) {
    const int q = qbase + j;
    const double X = (double)p1[3*q], Y = (double)p1[3*q+1], Z = (double)p1[3*q+2];
    qxr[j] = (float)(R0*X + R1*Y + R2*Z + T0);  // fp32-rounded, matches ref pc
    qyr[j] = (float)(R3*X + R4*Y + R5*Z + T1);
    qzr[j] = (float)(R6*X + R7*Y + R8*Z + T2);
    axv[j] = -2.f*qxr[j]; ayv[j] = -2.f*qyr[j]; azv[j] = -2.f*qzr[j];
    best[j] = __builtin_inff(); bidx[j] = 0;
  }
  if (s == 0 && lane == 0) {
    #pragma unroll
    for (int j = 0; j < QPW; ++j)
      qlds[(g << 3) + j] = make_float4(qxr[j], qyr[j], qzr[j], 0.f);
  }
  __syncthreads();                          // staging + qlds visible

  // ---- NN scan: slice s = cands [s*2048, s*2048+2048), lane-contiguous ----
  const int cb = s << 11;
  #pragma unroll 8
  for (int kk = 0; kk < 32; ++kk) {
    const int cidx = cb + (kk << 6) + lane;
    float4 c = cand[cidx];                  // ds_read_b128, conflict-free
    #pragma unroll
    for (int j = 0; j < QPW; ++j) {
      float d = fmaf(axv[j], c.x, fmaf(ayv[j], c.y, fmaf(azv[j], c.z, c.w)));
      if (d < best[j]) { best[j] = d; bidx[j] = cidx; }
    }
  }

  // ---- cross-lane argmin: packed (ordered-dist, idx) u64 butterfly ----
  unsigned long long pk[QPW];
  #pragma unroll
  for (int j = 0; j < QPW; ++j) {
    unsigned u = __float_as_uint(best[j]);
    u ^= (unsigned)((int)u >> 31) | 0x80000000u;   // monotone float->uint
    pk[j] = ((unsigned long long)u << 32) | (unsigned)bidx[j];
  }
  #pragma unroll
  for (int j = 0; j < QPW; ++j) {
    #pragma unroll
    for (int o = 1; o < 64; o <<= 1) {
      unsigned long long other = __shfl_xor(pk[j], o, 64);
      pk[j] = (other < pk[j]) ? other : pk[j];
    }
  }
  if (lane == 0) {
    #pragma unroll
    for (int j = 0; j < QPW; ++j)
      pkbuf[(g << 3) + j][s] = pk[j];
  }
  __syncthreads();

  // ---- combine 4 slices + pair sums: tid<32, one query each, all static ----
  if (tid < 32) {
    unsigned long long m = pkbuf[tid][0];
    unsigned long long m1 = pkbuf[tid][1]; m = (m1 < m) ? m1 : m;
    unsigned long long m2 = pkbuf[tid][2]; m = (m2 < m) ? m2 : m;
    unsigned long long m3 = pkbuf[tid][3]; m = (m3 < m) ? m3 : m;
    const unsigned idx = (unsigned)(m & 0xffffffffull);
    const float4 q4 = qlds[tid];
    const float4 b4 = cand[idx];
    const double ax = q4.x, ay = q4.y, az = q4.z;
    const double bx = b4.x, by = b4.y, bz = b4.z;
    const double d2 = (ax*ax + ay*ay + az*az) + (bx*bx + by*by + bz*bz)
                    - 2.0*(ax*bx + ay*by + az*bz);
    pairbuf[tid][0]  = sqrt(fmax(d2, 1e-12));
    pairbuf[tid][1]  = ax;    pairbuf[tid][2]  = ay;    pairbuf[tid][3]  = az;
    pairbuf[tid][4]  = bx;    pairbuf[tid][5]  = by;    pairbuf[tid][6]  = bz;
    pairbuf[tid][7]  = ax*bx; pairbuf[tid][8]  = ax*by; pairbuf[tid][9]  = ax*bz;
    pairbuf[tid][10] = ay*bx; pairbuf[tid][11] = ay*by; pairbuf[tid][12] = ay*bz;
    pairbuf[tid][13] = az*bx; pairbuf[tid][14] = az*by; pairbuf[tid][15] = az*bz;
  }
  __syncthreads();

  // ---- 16 column sums -> plain stores (coherent at kernel boundary) ----
  if (tid < 16) {
    double ssum = 0.0;
    #pragma unroll
    for (int i = 0; i < 32; ++i) ssum += pairbuf[i][tid];
    partOut[(blockIdx.x << 4) + tid] = ssum;
  }
}

// ---------------------------------------------------------------------------
// final (1 block): solve step 20 (if still active) and emit [R | t] 3x4.
// kabsch(p1, Rc*p1+tc) == (Rc, tc) exactly, so out = cumulative transform.
// ---------------------------------------------------------------------------
__global__ __launch_bounds__(256) void icp_final(const IcpSt* __restrict__ stIn,
                                                 const double* __restrict__ partIn,
                                                 float* __restrict__ out) {
  __shared__ double lds[64];
  __shared__ double tot[16];
  const int lane = threadIdx.x & 63;
  const int w    = threadIdx.x >> 6;

  if (stIn->done) {
    if (threadIdx.x == 0) {
      #pragma unroll
      for (int i = 0; i < 3; ++i) {
        out[4*i + 0] = (float)stIn->Rc[3*i + 0];
        out[4*i + 1] = (float)stIn->Rc[3*i + 1];
        out[4*i + 2] = (float)stIn->Rc[3*i + 2];
        out[4*i + 3] = (float)stIn->tc[i];
      }
    }
    return;
  }

  double v[16];
  const double* row = partIn + (threadIdx.x << 4);
  #pragma unroll
  for (int c = 0; c < 16; ++c) v[c] = row[c];
  #pragma unroll
  for (int q = 0; q < 16; ++q) {
    double x = v[q];
    for (int o = 32; o > 0; o >>= 1) x += __shfl_down(x, o, 64);
    if (lane == 0) lds[w*16 + q] = x;
  }
  __syncthreads();
  if (threadIdx.x < 16)
    tot[threadIdx.x] = lds[threadIdx.x] + lds[16 + threadIdx.x]
                     + lds[32 + threadIdx.x] + lds[48 + threadIdx.x];
  __syncthreads();

  if (threadIdx.x == 0) {
    double sm[16];
    #pragma unroll
    for (int i = 0; i < 16; ++i) sm[i] = tot[i];
    double Rn[9], tn[3], errnew; int dn;
    solve_compose(sm, stIn, Rn, tn, &errnew, &dn);
    #pragma unroll
    for (int i = 0; i < 3; ++i) {
      out[4*i + 0] = (float)Rn[3*i + 0];
      out[4*i + 1] = (float)Rn[3*i + 1];
      out[4*i + 2] = (float)Rn[3*i + 2];
      out[4*i + 3] = (float)tn[i];
    }
  }
}

// ---------------------------------------------------------------------------
extern "C" void kernel_launch(void* const* d_in, const int* in_sizes, int n_in,
                              void* d_out, int out_size, void* d_ws, size_t ws_size,
                              hipStream_t stream) {
  const float* p1 = (const float*)d_in[0];
  const float* p2 = (const float*)d_in[1];
  float* out = (float*)d_out;

  char* ws = (char*)d_ws;
  float4* p2aug = (float4*)ws;                            // 128 KiB
  IcpSt* st0    = (IcpSt*)(ws + 128*1024);                // slot 0
  IcpSt* st1    = (IcpSt*)(ws + 128*1024 + 256);          // slot 1
  double* part0 = (double*)(ws + 128*1024 + 1024);        // 32 KiB
  double* part1 = (double*)(ws + 128*1024 + 1024 + 32*1024);

  IcpSt* st[2]    = { st0, st1 };
  double* part[2] = { part0, part1 };

  icp_prep<<<N_PTS/256, 256, 0, stream>>>(p2, p2aug, st0);
  for (int k = 0; k < ICP_STEPS; ++k) {
    const IcpSt* stIn   = (k == 0) ? st0 : st[(k-1) & 1];
    IcpSt* stOut        = st[k & 1];          // unused when k==0 (no solve)
    const double* pIn   = part[(k+1) & 1];    // = part[(k-1)&1]; unused k==0
    double* pOut        = part[k & 1];
    if (k == 0) stOut = st1;                  // keep st0 (identity) intact
    icp_iter<<<NBLK, BSIZE, 0, stream>>>(p1, p2aug, stIn, stOut, pIn, pOut, k);
  }
  // solve for step 20: state_20 in slot (20&1)=0, part_20 in slot 0
  icp_final<<<1, 256, 0, stream>>>(st[0], part[0], out);
}